// Round 1
// baseline (223.504 us; speedup 1.0000x reference)
//
#include <hip/hip_runtime.h>
#include <stdint.h>

#define BB 32
#define IC 128
#define OC 128
#define HH 56
#define WW 56
#define ZD 512
#define NRS 9
#define OI (OC*IC)            // 16384
#define WROWS (OI*NRS)        // 147456
#define WDIM 58               // padded LDS width index u = w_in+1, 0..57

typedef float  f32x4  __attribute__((ext_vector_type(4)));
typedef short  bf16x8 __attribute__((ext_vector_type(8)));

static __device__ __forceinline__ short f2bf(float f) {
    uint32_t u = __float_as_uint(f);
    uint32_t r = (u + 0x7fffu + ((u >> 16) & 1u)) >> 16;
    return (short)r;
}

// ---------------------------------------------------------------------------
// Kernel 1: hypernetwork head.  w[b, row] = dot(z[b,:], W_head[row,:]) + bias
// Output bf16, layout [b][rs][o][i]  (rs = 3*r+s), so conv can read 32KB slices.
// Block: 256 threads = 4 waves (wave := b-group of 8), 256 rows, k-chunks of 64.
// ---------------------------------------------------------------------------
__global__ __launch_bounds__(256) void head_kernel(
    const float* __restrict__ Wh, const float* __restrict__ z,
    const float* __restrict__ bh, short* __restrict__ wout)
{
    __shared__ __align__(16) char Wl[256 * 64 * 4];   // 64 KB
    __shared__ __align__(16) char Zl[32 * 64 * 4];    // 8 KB
    const int tid  = threadIdx.x;
    const int lane = tid & 63;
    const int bg   = tid >> 6;          // wave id == b-group (8 b each)
    const int rowbase = blockIdx.x * 256;
    const int bgswz = (bg & 3) << 4;

    float acc[4][8];
    #pragma unroll
    for (int r = 0; r < 4; ++r)
        #pragma unroll
        for (int b = 0; b < 8; ++b) acc[r][b] = 0.f;

    for (int kc = 0; kc < 8; ++kc) {
        if (kc) __syncthreads();
        // stage W chunk: 256 rows x 64 k  (coalesced), swizzle (row&15)<<4
        #pragma unroll
        for (int q = 0; q < 16; ++q) {
            int f = tid + 256 * q;
            int row = f >> 4, slot = f & 15;
            f32x4 v = *(const f32x4*)(Wh + (size_t)(rowbase + row) * ZD + kc * 64 + slot * 4);
            *(f32x4*)(Wl + row * 256 + ((slot * 16) ^ ((row & 15) << 4))) = v;
        }
        // stage z chunk: 32 x 64, swizzle ((b>>3)&3)<<4
        #pragma unroll
        for (int q = 0; q < 2; ++q) {
            int f = tid + 256 * q;
            int b = f >> 4, slot = f & 15;
            f32x4 v = *(const f32x4*)(z + (size_t)b * ZD + kc * 64 + slot * 4);
            *(f32x4*)(Zl + b * 256 + ((slot * 16) ^ (((b >> 3) & 3) << 4))) = v;
        }
        __syncthreads();
        #pragma unroll
        for (int k4 = 0; k4 < 16; ++k4) {
            f32x4 wv[4];
            #pragma unroll
            for (int rr = 0; rr < 4; ++rr)
                wv[rr] = *(const f32x4*)(Wl + (rr * 64 + lane) * 256 +
                                         ((k4 * 16) ^ ((lane & 15) << 4)));
            #pragma unroll
            for (int bb = 0; bb < 8; ++bb) {
                f32x4 zv = *(const f32x4*)(Zl + (bg * 8 + bb) * 256 + ((k4 * 16) ^ bgswz));
                #pragma unroll
                for (int rr = 0; rr < 4; ++rr) {
                    acc[rr][bb] += wv[rr].x * zv.x;
                    acc[rr][bb] += wv[rr].y * zv.y;
                    acc[rr][bb] += wv[rr].z * zv.z;
                    acc[rr][bb] += wv[rr].w * zv.w;
                }
            }
        }
    }
    // bias + scattered bf16 stores to [b][rs][oi]
    #pragma unroll
    for (int rr = 0; rr < 4; ++rr) {
        int rowg = rowbase + rr * 64 + lane;
        float bias = bh[rowg];
        int oi = rowg / 9;
        int rs = rowg - oi * 9;
        size_t outb = (size_t)rs * OI + oi;
        #pragma unroll
        for (int bb = 0; bb < 8; ++bb) {
            float v = acc[rr][bb] + bias;
            wout[(size_t)(bg * 8 + bb) * WROWS + outb] = f2bf(v);
        }
    }
}

// ---------------------------------------------------------------------------
// Kernel 2: x [b][i][h][w] fp32  ->  xt [b][h][w][i] bf16
// ---------------------------------------------------------------------------
__global__ __launch_bounds__(256) void transpose_kernel(
    const float* __restrict__ x, short* __restrict__ xt)
{
    const int h = blockIdx.x;          // 56
    const int b = blockIdx.y;          // 32
    const int w = threadIdx.x & 63;
    const int yq = threadIdx.x >> 6;   // 0..3
    if (w >= WW) return;
    const float* xp = x + (size_t)b * IC * HH * WW + h * WW + w;
    short* op = xt + (((size_t)(b * HH + h)) * WW + w) * IC;
    #pragma unroll
    for (int q = 0; q < 4; ++q) {
        int ic = yq * 4 + q;           // 0..15
        bf16x8 pk;
        #pragma unroll
        for (int j = 0; j < 8; ++j) {
            float v = xp[(size_t)(ic * 8 + j) * (HH * WW)];
            pk[j] = f2bf(v);
        }
        *(bf16x8*)(op + ic * 8) = pk;
    }
}

// ---------------------------------------------------------------------------
// Kernel 3: per-sample conv as 9 shifted GEMMs with bf16 MFMA.
// Block = (h, b); 4 waves; wave owns o-frags {2wv, 2wv+1} x p-frags 0..3.
// X LDS [3][58][128] bf16 swizzled byte^=((u&7)<<4); W LDS [128][128] same.
// ---------------------------------------------------------------------------
__global__ __launch_bounds__(256) void conv_kernel(
    const short* __restrict__ wbf,   // [b][rs][o][i] bf16
    const short* __restrict__ xt,    // [b][h][w][i]  bf16
    float* __restrict__ out)         // [b][o][h][w]  fp32
{
    __shared__ __align__(16) char Xl[3 * WDIM * 256];  // 44544 B
    __shared__ __align__(16) char Wl[128 * 256];       // 32768 B
    const int tid  = threadIdx.x;
    const int lane = tid & 63;
    const int wv   = tid >> 6;       // wave 0..3
    const int h = blockIdx.x;        // 56
    const int b = blockIdx.y;        // 32

    // zero entire X region (covers halo + missing h-border rows)
    #pragma unroll
    for (int q = 0; q < 11; ++q) {
        int idx = tid + q * 256;
        if (idx < 3 * WDIM * 16) ((f32x4*)Xl)[idx] = (f32x4){0.f, 0.f, 0.f, 0.f};
    }
    __syncthreads();

    // stage X rows (async, source pre-swizzled so linear LDS dest == swizzled layout)
    for (int r = 0; r < 3; ++r) {
        int hin = h + r - 1;
        if (hin < 0 || hin >= HH) continue;
        const char* src = (const char*)(xt + ((size_t)(b * HH + hin)) * WW * IC);
        char* dstbase = Xl + (r * WDIM + 1) * 256;
        for (int it = wv; it < 14; it += 4) {
            int c = it * 64 + lane;
            int u = r * WDIM + 1 + (c >> 4);
            int soff = (c * 16) ^ ((u & 7) << 4);
            __builtin_amdgcn_global_load_lds(
                (const __attribute__((address_space(1))) uint32_t*)(src + soff),
                (__attribute__((address_space(3))) uint32_t*)(dstbase + it * 1024),
                16, 0, 0);
        }
    }
    // first __syncthreads in rs-loop drains vmcnt -> X ready

    f32x4 acc[2][4];
    #pragma unroll
    for (int a = 0; a < 2; ++a)
        #pragma unroll
        for (int p = 0; p < 4; ++p) acc[a][p] = (f32x4){0.f, 0.f, 0.f, 0.f};

    const int axor = (lane & 7) << 4;
    int kkoff[4];
    #pragma unroll
    for (int kk = 0; kk < 4; ++kk) kkoff[kk] = kk * 64 + ((lane >> 4) << 4);

    for (int rs = 0; rs < 9; ++rs) {
        __syncthreads();   // previous compute done reading Wl (and X gloads drained)
        // stage W slice [128][128] bf16, pre-swizzled source
        const char* wsrc = (const char*)(wbf + ((size_t)b * NRS + rs) * OI);
        for (int it = wv; it < 32; it += 4) {
            int c = it * 64 + lane;
            int soff = (c * 16) ^ (((c >> 4) & 7) << 4);
            __builtin_amdgcn_global_load_lds(
                (const __attribute__((address_space(1))) uint32_t*)(wsrc + soff),
                (__attribute__((address_space(3))) uint32_t*)(Wl + it * 1024),
                16, 0, 0);
        }
        __syncthreads();   // W staged

        const int r = rs / 3, s = rs - 3 * (rs / 3);
        int ubase[4], bswz[4];
        #pragma unroll
        for (int pf = 0; pf < 4; ++pf) {
            int p = pf * 16 + (lane & 15);
            int pc = p > 55 ? 55 : p;        // clamp garbage lanes in-bounds
            int uu = r * WDIM + pc + s;      // = r*58 + (w_in+1)
            ubase[pf] = uu * 256;
            bswz[pf] = (uu & 7) << 4;
        }
        #pragma unroll
        for (int kk = 0; kk < 4; ++kk) {
            bf16x8 a0 = *(const bf16x8*)(Wl + (wv * 32 + (lane & 15)) * 256 +
                                         (kkoff[kk] ^ axor));
            bf16x8 a1 = *(const bf16x8*)(Wl + (wv * 32 + 16 + (lane & 15)) * 256 +
                                         (kkoff[kk] ^ axor));
            #pragma unroll
            for (int pf = 0; pf < 4; ++pf) {
                bf16x8 bv = *(const bf16x8*)(Xl + ubase[pf] + (kkoff[kk] ^ bswz[pf]));
                acc[0][pf] = __builtin_amdgcn_mfma_f32_16x16x32_bf16(a0, bv, acc[0][pf], 0, 0, 0);
                acc[1][pf] = __builtin_amdgcn_mfma_f32_16x16x32_bf16(a1, bv, acc[1][pf], 0, 0, 0);
            }
        }
    }

    // epilogue: D col = lane&15 (=p), row = 4*(lane>>4)+reg (=o offset)
    const int pcol = lane & 15;
    const int rowq = lane >> 4;
    #pragma unroll
    for (int a = 0; a < 2; ++a) {
        int o0 = wv * 32 + a * 16 + rowq * 4;
        #pragma unroll
        for (int pf = 0; pf < 4; ++pf) {
            int p = pf * 16 + pcol;
            if (p < WW) {
                #pragma unroll
                for (int reg = 0; reg < 4; ++reg) {
                    out[(((size_t)b * OC + (o0 + reg)) * HH + h) * WW + p] = acc[a][pf][reg];
                }
            }
        }
    }
}

extern "C" void kernel_launch(void* const* d_in, const int* in_sizes, int n_in,
                              void* d_out, int out_size, void* d_ws, size_t ws_size,
                              hipStream_t stream) {
    const float* x  = (const float*)d_in[0];   // [32,128,56,56]
    const float* z  = (const float*)d_in[1];   // [32,512]
    const float* Wh = (const float*)d_in[2];   // [147456,512]
    const float* bh = (const float*)d_in[3];   // [147456]
    float* out = (float*)d_out;

    short* wbf = (short*)d_ws;                               // 9,437,184 B
    short* xt  = (short*)((char*)d_ws + (size_t)BB * NRS * OI * 2);  // +25,690,112 B

    head_kernel<<<dim3(WROWS / 256), 256, 0, stream>>>(Wh, z, bh, wbf);
    transpose_kernel<<<dim3(HH, BB), 256, 0, stream>>>(x, xt);
    conv_kernel<<<dim3(HH, BB), 256, 0, stream>>>(wbf, xt, out);
}

// Round 2
// 172.802 us; speedup vs baseline: 1.2934x; 1.2934x over previous
//
#include <hip/hip_runtime.h>
#include <hip/hip_bf16.h>
#include <stdint.h>

#define BB 32
#define IC 128
#define OC 128
#define HH 56
#define WW 56
#define ZD 512
#define NRS 9
#define OI (OC*IC)            // 16384
#define WROWS (OI*NRS)        // 147456
#define WDIM 58               // padded LDS width index u = w_in+1, 0..57

typedef float  f32x4  __attribute__((ext_vector_type(4)));
typedef short  bf16x8 __attribute__((ext_vector_type(8)));

static __device__ __forceinline__ short f2bf(float f) {
    uint32_t u = __float_as_uint(f);
    uint32_t r = (u + 0x7fffu + ((u >> 16) & 1u)) >> 16;
    return (short)r;
}
static __device__ __forceinline__ short f2bf_hw(float f) {
    __hip_bfloat16 h = __float2bfloat16(f);
    return *reinterpret_cast<short*>(&h);
}

// ---------------------------------------------------------------------------
// Kernel 1: hypernetwork head via MFMA.  w[b,row] = dot(z[b,:], Wh[row,:]) + bias
// A = z (16 b x 32 k, two b-tiles), B = Wh rows loaded global->VGPR, cvt bf16.
// Wave owns 16 rows; block = 4 waves = 64 rows; grid 2304 blocks.
// Lane reads row rowbase+(l&15), k-chunk (l>>4)*8: per instr 16 x 128B aligned
// fully-consumed L2 lines. Output bf16 [b][rs][o][i] for the conv.
// ---------------------------------------------------------------------------
__global__ __launch_bounds__(256) void head_kernel(
    const float* __restrict__ Wh, const float* __restrict__ z,
    const float* __restrict__ bh, short* __restrict__ wout)
{
    __shared__ __align__(16) char Zl[32 * 1024];   // z bf16, XOR-swizzled, 32 KB
    const int tid = threadIdx.x;

    // stage z: thread t -> b = t>>3, k-range (t&7)*64..+63, swizzle ^((b&7)<<4)
    {
        const int b = tid >> 3, ks = (tid & 7) * 64;
        const float* zp = z + (size_t)b * ZD + ks;
        const int bx = (b & 7) << 4;
        #pragma unroll
        for (int j8 = 0; j8 < 8; ++j8) {
            f32x4 v0 = *(const f32x4*)(zp + j8 * 8);
            f32x4 v1 = *(const f32x4*)(zp + j8 * 8 + 4);
            bf16x8 pk;
            pk[0] = f2bf_hw(v0.x); pk[1] = f2bf_hw(v0.y);
            pk[2] = f2bf_hw(v0.z); pk[3] = f2bf_hw(v0.w);
            pk[4] = f2bf_hw(v1.x); pk[5] = f2bf_hw(v1.y);
            pk[6] = f2bf_hw(v1.z); pk[7] = f2bf_hw(v1.w);
            *(bf16x8*)(Zl + b * 1024 + ((ks * 2 + j8 * 16) ^ bx)) = pk;
        }
    }
    __syncthreads();

    const int lane = tid & 63;
    const int wv   = tid >> 6;
    const int rl   = lane & 15;          // local row / b-index within tile
    const int kq   = lane >> 4;          // k-quadrant (8 floats each)
    const int rowg = blockIdx.x * 64 + wv * 16 + rl;
    const float* wp = Wh + (size_t)rowg * ZD + kq * 8;
    const int zxor = (rl & 7) << 4;

    f32x4 acc0 = {0.f, 0.f, 0.f, 0.f}, acc1 = {0.f, 0.f, 0.f, 0.f};
    #pragma unroll 4
    for (int kb = 0; kb < 16; ++kb) {
        f32x4 w0 = *(const f32x4*)(wp + kb * 32);
        f32x4 w1 = *(const f32x4*)(wp + kb * 32 + 4);
        bf16x8 bw;
        bw[0] = f2bf_hw(w0.x); bw[1] = f2bf_hw(w0.y);
        bw[2] = f2bf_hw(w0.z); bw[3] = f2bf_hw(w0.w);
        bw[4] = f2bf_hw(w1.x); bw[5] = f2bf_hw(w1.y);
        bw[6] = f2bf_hw(w1.z); bw[7] = f2bf_hw(w1.w);
        const int koff = (kb * 64 + kq * 16) ^ zxor;
        bf16x8 a0 = *(const bf16x8*)(Zl + rl * 1024 + koff);
        bf16x8 a1 = *(const bf16x8*)(Zl + (16 + rl) * 1024 + koff);
        acc0 = __builtin_amdgcn_mfma_f32_16x16x32_bf16(a0, bw, acc0, 0, 0, 0);
        acc1 = __builtin_amdgcn_mfma_f32_16x16x32_bf16(a1, bw, acc1, 0, 0, 0);
    }

    // D: col = lane&15 (= row rowg), row = 4*(lane>>4)+reg (= batch b)
    const float bias = bh[rowg];
    const int oi = rowg / 9, rs = rowg - oi * 9;
    const size_t outb = (size_t)rs * OI + oi;
    #pragma unroll
    for (int r = 0; r < 4; ++r) {
        const int b0 = kq * 4 + r;
        wout[(size_t)b0 * WROWS + outb]        = f2bf(acc0[r] + bias);
        wout[(size_t)(16 + b0) * WROWS + outb] = f2bf(acc1[r] + bias);
    }
}

// ---------------------------------------------------------------------------
// Kernel 2: x [b][i][h][w] fp32  ->  xt [b][h][w][i] bf16
// ---------------------------------------------------------------------------
__global__ __launch_bounds__(256) void transpose_kernel(
    const float* __restrict__ x, short* __restrict__ xt)
{
    const int h = blockIdx.x;          // 56
    const int b = blockIdx.y;          // 32
    const int w = threadIdx.x & 63;
    const int yq = threadIdx.x >> 6;   // 0..3
    if (w >= WW) return;
    const float* xp = x + (size_t)b * IC * HH * WW + h * WW + w;
    short* op = xt + (((size_t)(b * HH + h)) * WW + w) * IC;
    #pragma unroll
    for (int q = 0; q < 4; ++q) {
        int ic = yq * 4 + q;           // 0..15
        bf16x8 pk;
        #pragma unroll
        for (int j = 0; j < 8; ++j) {
            float v = xp[(size_t)(ic * 8 + j) * (HH * WW)];
            pk[j] = f2bf(v);
        }
        *(bf16x8*)(op + ic * 8) = pk;
    }
}

// ---------------------------------------------------------------------------
// Kernel 3: per-sample conv as 9 shifted GEMMs with bf16 MFMA.
// Block = (h, b); 4 waves; wave owns o-frags {2wv, 2wv+1} x p-frags 0..3.
// X LDS [3][58][128] bf16 swizzled byte^=((u&7)<<4); W LDS [128][128] same.
// ---------------------------------------------------------------------------
__global__ __launch_bounds__(256) void conv_kernel(
    const short* __restrict__ wbf,   // [b][rs][o][i] bf16
    const short* __restrict__ xt,    // [b][h][w][i]  bf16
    float* __restrict__ out)         // [b][o][h][w]  fp32
{
    __shared__ __align__(16) char Xl[3 * WDIM * 256];  // 44544 B
    __shared__ __align__(16) char Wl[128 * 256];       // 32768 B
    const int tid  = threadIdx.x;
    const int lane = tid & 63;
    const int wv   = tid >> 6;       // wave 0..3
    const int h = blockIdx.x;        // 56
    const int b = blockIdx.y;        // 32

    // zero entire X region (covers halo + missing h-border rows)
    #pragma unroll
    for (int q = 0; q < 11; ++q) {
        int idx = tid + q * 256;
        if (idx < 3 * WDIM * 16) ((f32x4*)Xl)[idx] = (f32x4){0.f, 0.f, 0.f, 0.f};
    }
    __syncthreads();

    // stage X rows (async, source pre-swizzled so linear LDS dest == swizzled layout)
    for (int r = 0; r < 3; ++r) {
        int hin = h + r - 1;
        if (hin < 0 || hin >= HH) continue;
        const char* src = (const char*)(xt + ((size_t)(b * HH + hin)) * WW * IC);
        char* dstbase = Xl + (r * WDIM + 1) * 256;
        for (int it = wv; it < 14; it += 4) {
            int c = it * 64 + lane;
            int u = r * WDIM + 1 + (c >> 4);
            int soff = (c * 16) ^ ((u & 7) << 4);
            __builtin_amdgcn_global_load_lds(
                (const __attribute__((address_space(1))) uint32_t*)(src + soff),
                (__attribute__((address_space(3))) uint32_t*)(dstbase + it * 1024),
                16, 0, 0);
        }
    }
    // first __syncthreads in rs-loop drains vmcnt -> X ready

    f32x4 acc[2][4];
    #pragma unroll
    for (int a = 0; a < 2; ++a)
        #pragma unroll
        for (int p = 0; p < 4; ++p) acc[a][p] = (f32x4){0.f, 0.f, 0.f, 0.f};

    const int axor = (lane & 7) << 4;
    int kkoff[4];
    #pragma unroll
    for (int kk = 0; kk < 4; ++kk) kkoff[kk] = kk * 64 + ((lane >> 4) << 4);

    for (int rs = 0; rs < 9; ++rs) {
        __syncthreads();   // previous compute done reading Wl (and X gloads drained)
        // stage W slice [128][128] bf16, pre-swizzled source
        const char* wsrc = (const char*)(wbf + ((size_t)b * NRS + rs) * OI);
        for (int it = wv; it < 32; it += 4) {
            int c = it * 64 + lane;
            int soff = (c * 16) ^ (((c >> 4) & 7) << 4);
            __builtin_amdgcn_global_load_lds(
                (const __attribute__((address_space(1))) uint32_t*)(wsrc + soff),
                (__attribute__((address_space(3))) uint32_t*)(Wl + it * 1024),
                16, 0, 0);
        }
        __syncthreads();   // W staged

        const int r = rs / 3, s = rs - 3 * (rs / 3);
        int ubase[4], bswz[4];
        #pragma unroll
        for (int pf = 0; pf < 4; ++pf) {
            int p = pf * 16 + (lane & 15);
            int pc = p > 55 ? 55 : p;        // clamp garbage lanes in-bounds
            int uu = r * WDIM + pc + s;      // = r*58 + (w_in+1)
            ubase[pf] = uu * 256;
            bswz[pf] = (uu & 7) << 4;
        }
        #pragma unroll
        for (int kk = 0; kk < 4; ++kk) {
            bf16x8 a0 = *(const bf16x8*)(Wl + (wv * 32 + (lane & 15)) * 256 +
                                         (kkoff[kk] ^ axor));
            bf16x8 a1 = *(const bf16x8*)(Wl + (wv * 32 + 16 + (lane & 15)) * 256 +
                                         (kkoff[kk] ^ axor));
            #pragma unroll
            for (int pf = 0; pf < 4; ++pf) {
                bf16x8 bv = *(const bf16x8*)(Xl + ubase[pf] + (kkoff[kk] ^ bswz[pf]));
                acc[0][pf] = __builtin_amdgcn_mfma_f32_16x16x32_bf16(a0, bv, acc[0][pf], 0, 0, 0);
                acc[1][pf] = __builtin_amdgcn_mfma_f32_16x16x32_bf16(a1, bv, acc[1][pf], 0, 0, 0);
            }
        }
    }

    // epilogue: D col = lane&15 (=p), row = 4*(lane>>4)+reg (=o offset)
    const int pcol = lane & 15;
    const int rowq = lane >> 4;
    #pragma unroll
    for (int a = 0; a < 2; ++a) {
        int o0 = wv * 32 + a * 16 + rowq * 4;
        #pragma unroll
        for (int pf = 0; pf < 4; ++pf) {
            int p = pf * 16 + pcol;
            if (p < WW) {
                #pragma unroll
                for (int reg = 0; reg < 4; ++reg) {
                    out[(((size_t)b * OC + (o0 + reg)) * HH + h) * WW + p] = acc[a][pf][reg];
                }
            }
        }
    }
}

extern "C" void kernel_launch(void* const* d_in, const int* in_sizes, int n_in,
                              void* d_out, int out_size, void* d_ws, size_t ws_size,
                              hipStream_t stream) {
    const float* x  = (const float*)d_in[0];   // [32,128,56,56]
    const float* z  = (const float*)d_in[1];   // [32,512]
    const float* Wh = (const float*)d_in[2];   // [147456,512]
    const float* bh = (const float*)d_in[3];   // [147456]
    float* out = (float*)d_out;

    short* wbf = (short*)d_ws;                               // 9,437,184 B
    short* xt  = (short*)((char*)d_ws + (size_t)BB * NRS * OI * 2);  // +25,690,112 B

    head_kernel<<<dim3(WROWS / 64), 256, 0, stream>>>(Wh, z, bh, wbf);
    transpose_kernel<<<dim3(HH, BB), 256, 0, stream>>>(x, xt);
    conv_kernel<<<dim3(HH, BB), 256, 0, stream>>>(wbf, xt, out);
}